// Round 5
// baseline (89.650 us; speedup 1.0000x reference)
//
#include <hip/hip_runtime.h>

#define BATCH 8192
#define NV 512
#define LD 64
#define RPB 16   // rows per block in main kernel

// ws layout (in floats):
//   [0..511]    r1min bits (uint, +inf init)
//   [512]       r2 sum accumulator
//   [1024..9215] xnorm[8192]

__global__ __launch_bounds__(256) void setup_kernel(const float* __restrict__ x,
                                                    unsigned* __restrict__ r1bits,
                                                    float* __restrict__ r2sum,
                                                    float* __restrict__ xnorm) {
  int tid = blockIdx.x * blockDim.x + threadIdx.x;
  if (tid < NV) r1bits[tid] = 0x7f800000u;  // +inf bits
  if (tid == 0) *r2sum = 0.f;
  if (tid < BATCH) {
    const float4* xr = (const float4*)(x + tid * LD);
    float acc = 0.f;
#pragma unroll
    for (int i = 0; i < LD / 4; ++i) {
      float4 v = xr[i];
      acc = fmaf(v.x, v.x, acc);
      acc = fmaf(v.y, v.y, acc);
      acc = fmaf(v.z, v.z, acc);
      acc = fmaf(v.w, v.w, acc);
    }
    xnorm[tid] = acc;
  }
}

__global__ __launch_bounds__(512) void dist_kernel(const float* __restrict__ x,
                                                   const float* __restrict__ p,
                                                   const float* __restrict__ xnorm,
                                                   float* __restrict__ out,
                                                   unsigned* __restrict__ r1bits,
                                                   float* __restrict__ r2sum) {
  const int v = threadIdx.x;          // codebook index owned by this thread
  const int r0 = blockIdx.x * RPB;    // first x-row for this block
  const int wave = v >> 6, lane = v & 63;
  __shared__ float wmin[RPB][8];

  // load this thread's codebook vector into registers (fully unrolled -> stays in VGPRs)
  float4 pv[LD / 4];
  const float4* pr = (const float4*)(p + v * LD);
#pragma unroll
  for (int i = 0; i < LD / 4; ++i) pv[i] = pr[i];

  float pn = 0.f;
#pragma unroll
  for (int i = 0; i < LD / 4; ++i) {
    pn = fmaf(pv[i].x, pv[i].x, pn);
    pn = fmaf(pv[i].y, pv[i].y, pn);
    pn = fmaf(pv[i].z, pv[i].z, pn);
    pn = fmaf(pv[i].w, pv[i].w, pn);
  }

  float vmin = 3.4e38f;  // running min over rows for this v (r1)

  for (int r = 0; r < RPB; ++r) {
    const int row = r0 + r;
    const float* xr = x + row * LD;  // uniform address -> scalar loads
    float a0 = 0.f, a1 = 0.f, a2 = 0.f, a3 = 0.f;
#pragma unroll
    for (int i = 0; i < LD / 4; ++i) {
      a0 = fmaf(xr[4 * i + 0], pv[i].x, a0);
      a1 = fmaf(xr[4 * i + 1], pv[i].y, a1);
      a2 = fmaf(xr[4 * i + 2], pv[i].z, a2);
      a3 = fmaf(xr[4 * i + 3], pv[i].w, a3);
    }
    float dot = (a0 + a1) + (a2 + a3);
    float d2 = xnorm[row] + pn - 2.f * dot;
    float dist = sqrtf(fmaxf(d2, 0.f));
    out[(long)row * NV + v] = dist;
    vmin = fminf(vmin, dist);

    // per-row min across the wave (for r2)
    float m = dist;
#pragma unroll
    for (int o = 32; o; o >>= 1) m = fminf(m, __shfl_xor(m, o));
    if (lane == 0) wmin[r][wave] = m;
  }

  atomicMin(&r1bits[v], __float_as_uint(vmin));

  __syncthreads();
  if (wave == 0) {
    float rm = 0.f;
    if (lane < RPB) {
      rm = wmin[lane][0];
#pragma unroll
      for (int w = 1; w < 8; ++w) rm = fminf(rm, wmin[lane][w]);
    }
    // sum the RPB row-mins (lanes >= RPB contribute 0)
#pragma unroll
    for (int o = 32; o; o >>= 1) rm += __shfl_xor(rm, o);
    if (lane == 0) atomicAdd(r2sum, rm);
  }
}

__global__ __launch_bounds__(512) void finalize_kernel(const unsigned* __restrict__ r1bits,
                                                       const float* __restrict__ r2sum,
                                                       float* __restrict__ out) {
  int tid = threadIdx.x;
  float val = __uint_as_float(r1bits[tid]);
#pragma unroll
  for (int o = 32; o; o >>= 1) val += __shfl_xor(val, o);
  __shared__ float ws[8];
  if ((tid & 63) == 0) ws[tid >> 6] = val;
  __syncthreads();
  if (tid == 0) {
    float s = 0.f;
    for (int w = 0; w < 8; ++w) s += ws[w];
    out[(long)BATCH * NV] = s / (float)NV;
    out[(long)BATCH * NV + 1] = r2sum[0] / (float)BATCH;
  }
}

extern "C" void kernel_launch(void* const* d_in, const int* in_sizes, int n_in,
                              void* d_out, int out_size, void* d_ws, size_t ws_size,
                              hipStream_t stream) {
  const float* x = (const float*)d_in[0];
  const float* p = (const float*)d_in[1];
  float* out = (float*)d_out;
  unsigned* r1bits = (unsigned*)d_ws;
  float* r2sum = (float*)d_ws + 512;
  float* xnorm = (float*)d_ws + 1024;

  hipLaunchKernelGGL(setup_kernel, dim3(BATCH / 256), dim3(256), 0, stream,
                     x, r1bits, r2sum, xnorm);
  hipLaunchKernelGGL(dist_kernel, dim3(BATCH / RPB), dim3(512), 0, stream,
                     x, p, xnorm, out, r1bits, r2sum);
  hipLaunchKernelGGL(finalize_kernel, dim3(1), dim3(512), 0, stream,
                     r1bits, r2sum, out);
}

// Round 13
// 87.010 us; speedup vs baseline: 1.0303x; 1.0303x over previous
//
#include <hip/hip_runtime.h>

#define BATCH 8192
#define NV 512
#define LD 64

typedef __attribute__((ext_vector_type(8))) short bf16x8;
typedef __attribute__((ext_vector_type(4))) float f32x4;

// ws layout (floats): [0..511] r1bits, [512] r2sum, [1024..9215] xnorm, [9216..9727] pnorm

static __device__ __forceinline__ short f2bf(float f) {  // RNE f32->bf16
  unsigned u = __float_as_uint(f);
  u += 0x7fff + ((u >> 16) & 1);
  return (short)(u >> 16);
}

static __device__ __forceinline__ bf16x8 load8_bf16(const float* ptr) {
  float4 f0 = *(const float4*)(ptr);
  float4 f1 = *(const float4*)(ptr + 4);
  bf16x8 r;
  r[0] = f2bf(f0.x); r[1] = f2bf(f0.y); r[2] = f2bf(f0.z); r[3] = f2bf(f0.w);
  r[4] = f2bf(f1.x); r[5] = f2bf(f1.y); r[6] = f2bf(f1.z); r[7] = f2bf(f1.w);
  return r;
}

__global__ __launch_bounds__(256) void setup_kernel(const float* __restrict__ x,
                                                    const float* __restrict__ p,
                                                    unsigned* __restrict__ r1bits,
                                                    float* __restrict__ r2sum,
                                                    float* __restrict__ xnorm,
                                                    float* __restrict__ pnorm) {
  int tid = blockIdx.x * blockDim.x + threadIdx.x;
  if (tid < NV) r1bits[tid] = 0x7f800000u;  // +inf
  if (tid == 0) *r2sum = 0.f;
  if (tid < BATCH) {
    const float4* xr = (const float4*)(x + tid * LD);
    float acc = 0.f;
#pragma unroll
    for (int i = 0; i < LD / 4; ++i) {
      float4 v = xr[i];
      acc = fmaf(v.x, v.x, acc); acc = fmaf(v.y, v.y, acc);
      acc = fmaf(v.z, v.z, acc); acc = fmaf(v.w, v.w, acc);
    }
    xnorm[tid] = acc;
  }
  if (tid < NV) {
    const float4* pr = (const float4*)(p + tid * LD);
    float acc = 0.f;
#pragma unroll
    for (int i = 0; i < LD / 4; ++i) {
      float4 v = pr[i];
      acc = fmaf(v.x, v.x, acc); acc = fmaf(v.y, v.y, acc);
      acc = fmaf(v.z, v.z, acc); acc = fmaf(v.w, v.w, acc);
    }
    pnorm[tid] = acc;
  }
}

// Block: 16 x-rows x all 512 cols. 8 waves, wave w owns cols [w*64, w*64+64).
// Per wave: 4 col-tiles of 16x16, K=64 -> 2 MFMAs each (mfma_f32_16x16x32_bf16).
// A-frag: lane holds x[r0 + (l&15)][kk*32 + (l>>4)*8 + j], j=0..7
// B-frag: lane holds p[col0 + (l&15)][kk*32 + (l>>4)*8 + j]
// D: col = l&15, row = (l>>4)*4 + reg   [verified layout, learn_hip m89/m91]
__global__ __launch_bounds__(512) void dist_kernel(const float* __restrict__ x,
                                                   const float* __restrict__ p,
                                                   const float* __restrict__ xn,
                                                   const float* __restrict__ pn,
                                                   float* __restrict__ out,
                                                   unsigned* __restrict__ r1bits,
                                                   float* __restrict__ r2sum) {
  const int tid = threadIdx.x;
  const int w = tid >> 6;
  const int lane = tid & 63;
  const int lhi = lane >> 4;   // 0..3
  const int llo = lane & 15;   // 0..15
  const int r0 = blockIdx.x << 4;   // 16 rows per block
  const int colbase = w * 64;

  __shared__ float r1buf[NV];
  __shared__ float r2buf[8][16];

  // A fragments (shared across the wave's 4 col-tiles)
  const float* arow = x + (r0 + llo) * LD;
  bf16x8 a0 = load8_bf16(arow + lhi * 8);
  bf16x8 a1 = load8_bf16(arow + 32 + lhi * 8);

  f32x4 acc0 = {0.f, 0.f, 0.f, 0.f}, acc1 = acc0, acc2 = acc0, acc3 = acc0;
  {
    const float* prow0 = p + (colbase + 0 * 16 + llo) * LD;
    acc0 = __builtin_amdgcn_mfma_f32_16x16x32_bf16(a0, load8_bf16(prow0 + lhi * 8), acc0, 0, 0, 0);
    acc0 = __builtin_amdgcn_mfma_f32_16x16x32_bf16(a1, load8_bf16(prow0 + 32 + lhi * 8), acc0, 0, 0, 0);
    const float* prow1 = p + (colbase + 1 * 16 + llo) * LD;
    acc1 = __builtin_amdgcn_mfma_f32_16x16x32_bf16(a0, load8_bf16(prow1 + lhi * 8), acc1, 0, 0, 0);
    acc1 = __builtin_amdgcn_mfma_f32_16x16x32_bf16(a1, load8_bf16(prow1 + 32 + lhi * 8), acc1, 0, 0, 0);
    const float* prow2 = p + (colbase + 2 * 16 + llo) * LD;
    acc2 = __builtin_amdgcn_mfma_f32_16x16x32_bf16(a0, load8_bf16(prow2 + lhi * 8), acc2, 0, 0, 0);
    acc2 = __builtin_amdgcn_mfma_f32_16x16x32_bf16(a1, load8_bf16(prow2 + 32 + lhi * 8), acc2, 0, 0, 0);
    const float* prow3 = p + (colbase + 3 * 16 + llo) * LD;
    acc3 = __builtin_amdgcn_mfma_f32_16x16x32_bf16(a0, load8_bf16(prow3 + lhi * 8), acc3, 0, 0, 0);
    acc3 = __builtin_amdgcn_mfma_f32_16x16x32_bf16(a1, load8_bf16(prow3 + 32 + lhi * 8), acc3, 0, 0, 0);
  }

  // epilogue: dist = sqrt(max(xn + pn - 2*dot, 0))
  float xnr[4];
#pragma unroll
  for (int r = 0; r < 4; ++r) xnr[r] = xn[r0 + lhi * 4 + r];

  float rmin[4] = {3.4e38f, 3.4e38f, 3.4e38f, 3.4e38f};
  float cmin[4];
#pragma unroll
  for (int t = 0; t < 4; ++t) {
    const int col = colbase + t * 16 + llo;
    const float pnc = pn[col];
    const f32x4 a = (t == 0) ? acc0 : (t == 1) ? acc1 : (t == 2) ? acc2 : acc3;
    float cm = 3.4e38f;
#pragma unroll
    for (int r = 0; r < 4; ++r) {
      float d2 = xnr[r] + pnc - 2.f * a[r];
      float dist = sqrtf(fmaxf(d2, 0.f));
      out[(long)(r0 + lhi * 4 + r) * NV + col] = dist;
      cm = fminf(cm, dist);
      rmin[r] = fminf(rmin[r], dist);
    }
    cmin[t] = cm;
  }

  // r1: per-col min over the block's 16 rows (combine the 4 lhi groups)
#pragma unroll
  for (int t = 0; t < 4; ++t) {
    float v = cmin[t];
    v = fminf(v, __shfl_xor(v, 16));
    v = fminf(v, __shfl_xor(v, 32));
    if (lane < 16) r1buf[colbase + t * 16 + lane] = v;
  }
  // r2: per-row min over this wave's 64 cols (reduce across 16 lanes in group)
#pragma unroll
  for (int r = 0; r < 4; ++r) {
    float v = rmin[r];
    v = fminf(v, __shfl_xor(v, 1));
    v = fminf(v, __shfl_xor(v, 2));
    v = fminf(v, __shfl_xor(v, 4));
    v = fminf(v, __shfl_xor(v, 8));
    if (llo == 0) r2buf[w][lhi * 4 + r] = v;
  }
  __syncthreads();

  atomicMin(&r1bits[tid], __float_as_uint(r1buf[tid]));

  if (tid < 16) {
    float v = r2buf[0][tid];
#pragma unroll
    for (int ww = 1; ww < 8; ++ww) v = fminf(v, r2buf[ww][tid]);
    v += __shfl_xor(v, 1);
    v += __shfl_xor(v, 2);
    v += __shfl_xor(v, 4);
    v += __shfl_xor(v, 8);
    if (tid == 0) atomicAdd(r2sum, v);
  }
}

__global__ __launch_bounds__(512) void finalize_kernel(const unsigned* __restrict__ r1bits,
                                                       const float* __restrict__ r2sum,
                                                       float* __restrict__ out) {
  int tid = threadIdx.x;
  float val = __uint_as_float(r1bits[tid]);
#pragma unroll
  for (int o = 32; o; o >>= 1) val += __shfl_xor(val, o);
  __shared__ float ws[8];
  if ((tid & 63) == 0) ws[tid >> 6] = val;
  __syncthreads();
  if (tid == 0) {
    float s = 0.f;
    for (int w = 0; w < 8; ++w) s += ws[w];
    out[(long)BATCH * NV] = s / (float)NV;
    out[(long)BATCH * NV + 1] = r2sum[0] / (float)BATCH;
  }
}

extern "C" void kernel_launch(void* const* d_in, const int* in_sizes, int n_in,
                              void* d_out, int out_size, void* d_ws, size_t ws_size,
                              hipStream_t stream) {
  const float* x = (const float*)d_in[0];
  const float* p = (const float*)d_in[1];
  float* out = (float*)d_out;
  unsigned* r1bits = (unsigned*)d_ws;
  float* r2sum = (float*)d_ws + 512;
  float* xnorm = (float*)d_ws + 1024;
  float* pnorm = (float*)d_ws + 9216;

  hipLaunchKernelGGL(setup_kernel, dim3(BATCH / 256), dim3(256), 0, stream,
                     x, p, r1bits, r2sum, xnorm, pnorm);
  hipLaunchKernelGGL(dist_kernel, dim3(BATCH / 16), dim3(512), 0, stream,
                     x, p, xnorm, pnorm, out, r1bits, r2sum);
  hipLaunchKernelGGL(finalize_kernel, dim3(1), dim3(512), 0, stream,
                     r1bits, r2sum, out);
}

// Round 14
// 84.519 us; speedup vs baseline: 1.0607x; 1.0295x over previous
//
#include <hip/hip_runtime.h>

#define BATCH 8192
#define NV 512
#define LD 64

typedef __attribute__((ext_vector_type(8))) short bf16x8;
typedef __attribute__((ext_vector_type(4))) float f32x4;

// ws layout (floats): [0..511] r1bits, [512] r2sum

static __device__ __forceinline__ short f2bf(float f) {  // RNE f32->bf16
  unsigned u = __float_as_uint(f);
  u += 0x7fff + ((u >> 16) & 1);
  return (short)(u >> 16);
}

static __device__ __forceinline__ bf16x8 cvt8(float4 f0, float4 f1) {
  bf16x8 r;
  r[0] = f2bf(f0.x); r[1] = f2bf(f0.y); r[2] = f2bf(f0.z); r[3] = f2bf(f0.w);
  r[4] = f2bf(f1.x); r[5] = f2bf(f1.y); r[6] = f2bf(f1.z); r[7] = f2bf(f1.w);
  return r;
}

static __device__ __forceinline__ float sq16(float4 a, float4 b, float4 c, float4 d) {
  float s = 0.f;
  s = fmaf(a.x, a.x, s); s = fmaf(a.y, a.y, s); s = fmaf(a.z, a.z, s); s = fmaf(a.w, a.w, s);
  s = fmaf(b.x, b.x, s); s = fmaf(b.y, b.y, s); s = fmaf(b.z, b.z, s); s = fmaf(b.w, b.w, s);
  s = fmaf(c.x, c.x, s); s = fmaf(c.y, c.y, s); s = fmaf(c.z, c.z, s); s = fmaf(c.w, c.w, s);
  s = fmaf(d.x, d.x, s); s = fmaf(d.y, d.y, s); s = fmaf(d.z, d.z, s); s = fmaf(d.w, d.w, s);
  return s;
}

__global__ __launch_bounds__(512) void init_kernel(unsigned* __restrict__ r1bits,
                                                   float* __restrict__ r2sum) {
  r1bits[threadIdx.x] = 0x7f800000u;  // +inf bits
  if (threadIdx.x == 0) *r2sum = 0.f;
}

// Block: 16 x-rows x all 512 cols. 8 waves; wave w owns cols [w*64, w*64+64).
// Norms computed inline from the f32 fragment loads (f32 precision), then
// fragments converted to bf16 for mfma_f32_16x16x32_bf16.
// A-frag: lane holds x[r0+(l&15)][kk*32+(l>>4)*8+j]; B-frag: p[col][same k].
// D: col = l&15, row = (l>>4)*4 + reg   [verified layout, learn_hip m89/m91]
__global__ __launch_bounds__(512) void dist_kernel(const float* __restrict__ x,
                                                   const float* __restrict__ p,
                                                   float* __restrict__ out,
                                                   unsigned* __restrict__ r1bits,
                                                   float* __restrict__ r2sum) {
  const int tid = threadIdx.x;
  const int w = tid >> 6, lane = tid & 63;
  const int lhi = lane >> 4, llo = lane & 15;
  const int r0 = blockIdx.x << 4;   // 16 rows per block
  const int colbase = w * 64;

  __shared__ float xn_s[8][16];   // per-wave copy of the block's 16 x-row norms
  __shared__ float r2buf[8][16];

  // ---- A fragments + x-row norm (row r0+llo), all in f32 first ----
  const float* arow = x + (r0 + llo) * LD;
  float4 xa0 = *(const float4*)(arow + lhi * 8);
  float4 xa1 = *(const float4*)(arow + lhi * 8 + 4);
  float4 xa2 = *(const float4*)(arow + 32 + lhi * 8);
  float4 xa3 = *(const float4*)(arow + 32 + lhi * 8 + 4);

  float s = sq16(xa0, xa1, xa2, xa3);
  s += __shfl_xor(s, 16);
  s += __shfl_xor(s, 32);           // now = ||x_row||^2 for row r0+llo
  if (lhi == 0) xn_s[w][llo] = s;   // within-wave write; read below (no barrier needed)

  bf16x8 a0 = cvt8(xa0, xa1), a1 = cvt8(xa2, xa3);

  // ---- B fragments + p-row norms + MFMA ----
  f32x4 acc[4];
  float pns[4];
#pragma unroll
  for (int t = 0; t < 4; ++t) {
    const float* prow = p + (colbase + t * 16 + llo) * LD;
    float4 pf0 = *(const float4*)(prow + lhi * 8);
    float4 pf1 = *(const float4*)(prow + lhi * 8 + 4);
    float4 pf2 = *(const float4*)(prow + 32 + lhi * 8);
    float4 pf3 = *(const float4*)(prow + 32 + lhi * 8 + 4);
    float ps = sq16(pf0, pf1, pf2, pf3);
    ps += __shfl_xor(ps, 16);
    ps += __shfl_xor(ps, 32);       // = ||p_col||^2 for col colbase+t*16+llo
    pns[t] = ps;                    // exactly the lane that needs it in the epilogue
    f32x4 z = {0.f, 0.f, 0.f, 0.f};
    z = __builtin_amdgcn_mfma_f32_16x16x32_bf16(a0, cvt8(pf0, pf1), z, 0, 0, 0);
    z = __builtin_amdgcn_mfma_f32_16x16x32_bf16(a1, cvt8(pf2, pf3), z, 0, 0, 0);
    acc[t] = z;
  }

  float xnr[4];
#pragma unroll
  for (int r = 0; r < 4; ++r) xnr[r] = xn_s[w][lhi * 4 + r];

  // ---- epilogue: dist = sqrt(max(xn + pn - 2*dot, 0)) + reductions ----
  float rmin[4] = {3.4e38f, 3.4e38f, 3.4e38f, 3.4e38f};
#pragma unroll
  for (int t = 0; t < 4; ++t) {
    const int col = colbase + t * 16 + llo;
    float cm = 3.4e38f;
#pragma unroll
    for (int r = 0; r < 4; ++r) {
      float d2 = xnr[r] + pns[t] - 2.f * acc[t][r];
      float dist = sqrtf(fmaxf(d2, 0.f));
      out[(long)(r0 + lhi * 4 + r) * NV + col] = dist;
      cm = fminf(cm, dist);
      rmin[r] = fminf(rmin[r], dist);
    }
    // r1: per-col min over the block's 16 rows, then one atomicMin per col
    cm = fminf(cm, __shfl_xor(cm, 16));
    cm = fminf(cm, __shfl_xor(cm, 32));
    if (lane < 16) atomicMin(&r1bits[colbase + t * 16 + lane], __float_as_uint(cm));
  }

  // r2: per-row min over this wave's 64 cols, combine across waves, one atomicAdd
#pragma unroll
  for (int r = 0; r < 4; ++r) {
    float v = rmin[r];
    v = fminf(v, __shfl_xor(v, 1));
    v = fminf(v, __shfl_xor(v, 2));
    v = fminf(v, __shfl_xor(v, 4));
    v = fminf(v, __shfl_xor(v, 8));
    if (llo == 0) r2buf[w][lhi * 4 + r] = v;
  }
  __syncthreads();
  if (tid < 16) {
    float v = r2buf[0][tid];
#pragma unroll
    for (int ww = 1; ww < 8; ++ww) v = fminf(v, r2buf[ww][tid]);
    v += __shfl_xor(v, 1);
    v += __shfl_xor(v, 2);
    v += __shfl_xor(v, 4);
    v += __shfl_xor(v, 8);
    if (tid == 0) atomicAdd(r2sum, v);
  }
}

__global__ __launch_bounds__(512) void finalize_kernel(const unsigned* __restrict__ r1bits,
                                                       const float* __restrict__ r2sum,
                                                       float* __restrict__ out) {
  int tid = threadIdx.x;
  float val = __uint_as_float(r1bits[tid]);
#pragma unroll
  for (int o = 32; o; o >>= 1) val += __shfl_xor(val, o);
  __shared__ float ws[8];
  if ((tid & 63) == 0) ws[tid >> 6] = val;
  __syncthreads();
  if (tid == 0) {
    float sum = 0.f;
    for (int w = 0; w < 8; ++w) sum += ws[w];
    out[(long)BATCH * NV] = sum / (float)NV;
    out[(long)BATCH * NV + 1] = r2sum[0] / (float)BATCH;
  }
}

extern "C" void kernel_launch(void* const* d_in, const int* in_sizes, int n_in,
                              void* d_out, int out_size, void* d_ws, size_t ws_size,
                              hipStream_t stream) {
  const float* x = (const float*)d_in[0];
  const float* p = (const float*)d_in[1];
  float* out = (float*)d_out;
  unsigned* r1bits = (unsigned*)d_ws;
  float* r2sum = (float*)d_ws + 512;

  hipLaunchKernelGGL(init_kernel, dim3(1), dim3(512), 0, stream, r1bits, r2sum);
  hipLaunchKernelGGL(dist_kernel, dim3(BATCH / 16), dim3(512), 0, stream,
                     x, p, out, r1bits, r2sum);
  hipLaunchKernelGGL(finalize_kernel, dim3(1), dim3(512), 0, stream,
                     r1bits, r2sum, out);
}